// Round 15
// baseline (94.835 us; speedup 1.0000x reference)
//
#include <hip/hip_runtime.h>
#include <hip/hip_fp16.h>
#include <cstddef>

// Deformable conv: x(8,128,128,64) f32, offsets(8,128,128,18) f32, W(64,9,128) f32
// out(8,128,128,128) f32.
//
// Round 15: M-split reg-direct A-frags (R14) + phase-0 LDS param tables (the
// R8->R9 proven fix: no per-tap dependent global offset loads) + counted-vmcnt
// barrier (T4: drain only the 4 gload_lds B-stage ops, keep the 8 next-tap
// gathers in flight across the barrier).
//   prepass A: x -> f16 xh; prepass B: W -> frag-ordered wt3[n][kf][nf][ln][8].
//   main: 2048 blocks (64 px), image-per-XCD swizzle, 4 waves x 16px x 128f.
//   Per tap: stage B(n+1) via global_load_lds | read params(n+1) from LDS |
//            blend->A-frag in regs | gather(n+1) | 16 MFMA | vmcnt(8)+s_barrier.

typedef __attribute__((ext_vector_type(8))) _Float16 f16x8;
typedef __attribute__((ext_vector_type(4))) float    f32x4;

struct __align__(16) H2x4 { __half2 a, b, c, d; };
union HV { H2x4 h; f16x8 v; };

// ---------------- prepass kernels ----------------

__global__ void cvt_x_kernel(const float* __restrict__ x, __half* __restrict__ xh) {
    int i = blockIdx.x * 256 + threadIdx.x;        // 1,048,576 threads * 8 elems
    const float4* p = (const float4*)x + (size_t)i * 2;
    float4 a = p[0], b = p[1];
    H2x4 o;
    o.a = __floats2half2_rn(a.x, a.y);
    o.b = __floats2half2_rn(a.z, a.w);
    o.c = __floats2half2_rn(b.x, b.y);
    o.d = __floats2half2_rn(b.z, b.w);
    ((H2x4*)xh)[i] = o;
}

// wt3[(((n*2+kf)*8+nf)*64+ln)*8+e] = W[c][n][f]
//   c = kf*32 + (ln>>4)*8 + e,  f = nf*16 + (ln&15).
// Per-tap chunk = 8192 halves = 16 KB, contiguous.
__global__ void cvt_w_kernel(const float* __restrict__ W, __half* __restrict__ wt3) {
    int idx = blockIdx.x * 256 + threadIdx.x;      // 73728 = 9*2*8*64*8
    if (idx >= 9 * 2 * 8 * 64 * 8) return;
    int e  = idx & 7;
    int ln = (idx >> 3) & 63;
    int nf = (idx >> 9) & 7;
    int kf = (idx >> 12) & 1;
    int n  = idx >> 13;
    int c = kf * 32 + (ln >> 4) * 8 + e;
    int f = nf * 16 + (ln & 15);
    wt3[idx] = __float2half_rn(W[((size_t)c * 9 + n) * 128 + f]);
}

// ---------------- main MFMA kernel ----------------

struct GT { uint4 v00, v01, v10, v11; };

__device__ inline void gload_lds16(const void* g, void* l) {
    __builtin_amdgcn_global_load_lds(
        (const __attribute__((address_space(1))) void*)g,
        (__attribute__((address_space(3))) void*)l, 16, 0, 0);
}

__device__ inline void gather4(const char* __restrict__ ximg, int cbase,
                               unsigned coff, GT& G)
{
    int i0 = cbase >> 7, j0 = cbase & 127;
    size_t b00 = ((size_t)cbase << 7) + coff;      // 128 B per pixel
    int di = (i0 < 127) ? (128 * 128) : 0;
    int dj = (j0 < 127) ? 128 : 0;
    G.v00 = *(const uint4*)(ximg + b00);
    G.v01 = *(const uint4*)(ximg + b00 + dj);
    G.v10 = *(const uint4*)(ximg + b00 + di);
    G.v11 = *(const uint4*)(ximg + b00 + di + dj);
}

__device__ inline f16x8 blend(const GT& G, __half2 wAi, __half2 wBi)
{
    __half2 w00 = __low2half2(wAi), w01 = __high2half2(wAi);
    __half2 w10 = __low2half2(wBi), w11 = __high2half2(wBi);
    HV a00, a01, a10, a11, r;
    a00.h = *(const H2x4*)&G.v00;
    a01.h = *(const H2x4*)&G.v01;
    a10.h = *(const H2x4*)&G.v10;
    a11.h = *(const H2x4*)&G.v11;
    r.h.a = __hfma2(a11.h.a, w11, __hfma2(a10.h.a, w10, __hfma2(a01.h.a, w01, __hmul2(a00.h.a, w00))));
    r.h.b = __hfma2(a11.h.b, w11, __hfma2(a10.h.b, w10, __hfma2(a01.h.b, w01, __hmul2(a00.h.b, w00))));
    r.h.c = __hfma2(a11.h.c, w11, __hfma2(a10.h.c, w10, __hfma2(a01.h.c, w01, __hmul2(a00.h.c, w00))));
    r.h.d = __hfma2(a11.h.d, w11, __hfma2(a10.h.d, w10, __hfma2(a01.h.d, w01, __hmul2(a00.h.d, w00))));
    return r.v;
}

__global__ __launch_bounds__(256, 4)
void defconv_mfma(const float* __restrict__ offs,
                  const __half* __restrict__ xh,
                  const __half* __restrict__ wt,
                  float* __restrict__ out)
{
    __shared__ char bshare[2][16384];              // per-tap B, double-buffered (32 KB)
    __shared__ unsigned short p_base[9][64];       // (i0<<7)|j0 per (tap, local px)
    __shared__ __half2 p_w[9][64][2];              // bilinear corner weights

    const int t = threadIdx.x;

    // XCD swizzle: dispatch i -> XCD i%8 (heuristic); give XCD k image k.
    int bid = blockIdx.x;
    int wq  = (bid & 7) * 256 + (bid >> 3);        // bijective, 2048 % 8 == 0
    const int m   = wq >> 8;                       // image == XCD
    const int h   = (wq >> 1) & 127;               // row
    const int q   = wq & 1;                        // px half (64)
    const int pxg = q * 64;

    const int ln = t & 63;
    const int wv = t >> 6;
    const int r  = ln & 15;
    const int g  = ln >> 4;
    const int lpx = wv * 16 + r;                   // local pixel (0..63)
    const int px0 = pxg + wv * 16;                 // wave's global px base

    const char* ximg = (const char*)(xh + (size_t)m * (128 * 128 * 64));

    const unsigned coff0 = (unsigned)(g * 16);        // kf=0: c 0..31, octet g
    const unsigned coff1 = (unsigned)(64 + g * 16);   // kf=1: c 32..63
    const unsigned boff  = (unsigned)(ln * 16);       // lane's B-frag byte offset
    const int sbase = wv * 1024 + ln * 16;            // wave-linear staging offset

    f32x4 acc[8] = {};

    // ---- stage tap-0 B via global_load_lds (overlaps phase 0) ----
    {
        const char* src = (const char*)wt;         // tap 0 chunk (16 KB)
        char* dst = bshare[0];
        gload_lds16(src + sbase,         dst + sbase);
        gload_lds16(src + sbase + 4096,  dst + sbase + 4096);
        gload_lds16(src + sbase + 8192,  dst + sbase + 8192);
        gload_lds16(src + sbase + 12288, dst + sbase + 12288);
    }

    // ---- phase 0: bilinear params per (px, tap) -> LDS (offsets read ONCE) ----
    const float* offrow = offs + ((size_t)((m * 128 + h) * 128 + pxg)) * 18;
    for (int i = t; i < 576; i += 256) {
        int px = i & 63, n = i >> 6;
        float o0 = offrow[px * 18 + 2 * n];
        float o1 = offrow[px * 18 + 2 * n + 1];
        float ci = fminf(fmaxf((float)h + o0, 0.f), 127.f);
        float cj = fminf(fmaxf((float)(pxg + px) + o1, 0.f), 127.f);
        int i0 = (int)ci;   // floor, ci >= 0
        int j0 = (int)cj;
        float fi = ci - (float)i0, fj = cj - (float)j0;
        float gi = 1.f - fi,       gj = 1.f - fj;
        p_base[n][px] = (unsigned short)((i0 << 7) | j0);
        p_w[n][px][0] = __floats2half2_rn(gi * gj, gi * fj);
        p_w[n][px][1] = __floats2half2_rn(fi * gj, fi * fj);
    }
    __syncthreads();   // param tables + tap-0 B staged (full drain, once)

    // ---- prologue: tap-0 params + gathers ----
    int cb_cur = p_base[0][lpx];
    __half2 wA_cur = p_w[0][lpx][0];
    __half2 wB_cur = p_w[0][lpx][1];
    GT G0, G1;
    gather4(ximg, cb_cur, coff0, G0);
    gather4(ximg, cb_cur, coff1, G1);

    for (int n = 0; n < 9; ++n) {
        const char* bcur = bshare[n & 1];

        // issue next tap's B-stage (global->LDS direct, zero VGPR cost)
        if (n < 8) {
            const char* src = (const char*)(wt + (size_t)(n + 1) * 8192);
            char* dst = bshare[(n + 1) & 1];
            gload_lds16(src + sbase,         dst + sbase);
            gload_lds16(src + sbase + 4096,  dst + sbase + 4096);
            gload_lds16(src + sbase + 8192,  dst + sbase + 8192);
            gload_lds16(src + sbase + 12288, dst + sbase + 12288);
        }

        // next tap's params from LDS (short latency, hides under blend/MFMA)
        int cb_nxt = cb_cur; __half2 wA_nxt = wA_cur, wB_nxt = wB_cur;
        if (n < 8) {
            cb_nxt = p_base[n + 1][lpx];
            wA_nxt = p_w[n + 1][lpx][0];
            wB_nxt = p_w[n + 1][lpx][1];
        }

        // ---- kf=0: blend (gathers issued last tap), refill, 8 MFMA ----
        f16x8 a0 = blend(G0, wA_cur, wB_cur);
        if (n < 8) gather4(ximg, cb_nxt, coff0, G0);

        __builtin_amdgcn_s_setprio(1);
#pragma unroll
        for (int nf = 0; nf < 8; ++nf) {
            f16x8 b = *(const f16x8*)(bcur + nf * 1024 + boff);
            acc[nf] = __builtin_amdgcn_mfma_f32_16x16x32_f16(a0, b, acc[nf], 0, 0, 0);
        }
        __builtin_amdgcn_s_setprio(0);

        // ---- kf=1 ----
        f16x8 a1 = blend(G1, wA_cur, wB_cur);
        if (n < 8) gather4(ximg, cb_nxt, coff1, G1);

        __builtin_amdgcn_s_setprio(1);
#pragma unroll
        for (int nf = 0; nf < 8; ++nf) {
            f16x8 b = *(const f16x8*)(bcur + 8192 + nf * 1024 + boff);
            acc[nf] = __builtin_amdgcn_mfma_f32_16x16x32_f16(a1, b, acc[nf], 0, 0, 0);
        }
        __builtin_amdgcn_s_setprio(0);

        // ---- counted-vmcnt barrier: drain ONLY the 4 B-stage ops (oldest);
        //      the 8 next-tap gathers stay in flight across the barrier. ----
        if (n < 8) {
            __builtin_amdgcn_sched_barrier(0);
            asm volatile("s_waitcnt vmcnt(8)" ::: "memory");
            __builtin_amdgcn_s_barrier();
            __builtin_amdgcn_sched_barrier(0);
        }

        cb_cur = cb_nxt; wA_cur = wA_nxt; wB_cur = wB_nxt;
    }

    // ---- epilogue: D[px][f], col(lane&15)=f, row=(lane>>4)*4+reg = px ----
    float* orow = out + (size_t)((m * 128 + h) * 128) * 128;
#pragma unroll
    for (int nf = 0; nf < 8; ++nf) {
        int f = nf * 16 + r;
#pragma unroll
        for (int qq = 0; qq < 4; ++qq)
            orow[(size_t)(px0 + g * 4 + qq) * 128 + f] = acc[nf][qq];
    }
}

// ---------------- fp32 fallback (if ws too small) ----------------

constexpr int Hh   = 128;
constexpr int Wdim = 128;
constexpr int Cc   = 64;
constexpr int NTAP = 9;
constexpr int Ff   = 128;
constexpr int PXB  = 128;
constexpr int SPAD = 132;

__global__ __launch_bounds__(256, 2)
void defconv_f32(const float* __restrict__ x,
                 const float* __restrict__ offs,
                 const float* __restrict__ Wt,
                 float* __restrict__ out)
{
    __shared__ float s_tile[Cc][SPAD];
    __shared__ float w_tile[Cc][Ff];
    __shared__ float off_lds[PXB * 2 * NTAP];

    const int t   = threadIdx.x;
    const int bid = blockIdx.x;
    const int m   = bid >> 7;
    const int h   = bid & 127;

    const float* offrow = offs + (size_t)(m * Hh + h) * Wdim * (2 * NTAP);
    for (int i = t; i < PXB * 2 * NTAP; i += 256) off_lds[i] = offrow[i];

    const int pg = t & 15;
    const int fg = t >> 4;
    const int p0 = pg * 8;
    const int f0 = fg * 8;

    float acc[8][8];
#pragma unroll
    for (int a = 0; a < 8; ++a)
#pragma unroll
        for (int b = 0; b < 8; ++b) acc[a][b] = 0.f;

    const float* xbase = x + (size_t)m * Hh * Wdim * Cc;
    __syncthreads();

    for (int n = 0; n < NTAP; ++n) {
#pragma unroll
        for (int i = 0; i < 8; ++i) {
            int idx = t + 256 * i;
            int c   = idx >> 5;
            int f4  = (idx & 31) * 4;
            *(float4*)&w_tile[c][f4] =
                *(const float4*)(Wt + ((size_t)c * NTAP + n) * Ff + f4);
        }
#pragma unroll
        for (int i = 0; i < 8; ++i) {
            int task = t + 256 * i;
            int px   = task >> 4;
            int c4   = (task & 15) * 4;
            float o0 = off_lds[px * (2 * NTAP) + 2 * n];
            float o1 = off_lds[px * (2 * NTAP) + 2 * n + 1];
            float ci = fminf(fmaxf((float)h  + o0, 0.f), 127.f);
            float cj = fminf(fmaxf((float)px + o1, 0.f), 127.f);
            int i0 = (int)floorf(ci);
            int i1 = (int)ceilf(ci);
            int j0 = (int)floorf(cj);
            int j1 = (int)ceilf(cj);
            float fi = ci - (float)i0;
            float fj = cj - (float)j0;
            const float* r00 = xbase + ((size_t)i0 * Wdim + j0) * Cc + c4;
            const float* r01 = xbase + ((size_t)i0 * Wdim + j1) * Cc + c4;
            const float* r10 = xbase + ((size_t)i1 * Wdim + j0) * Cc + c4;
            const float* r11 = xbase + ((size_t)i1 * Wdim + j1) * Cc + c4;
            float4 vlt = *(const float4*)r00;
            float4 vrt = *(const float4*)r01;
            float4 vlb = *(const float4*)r10;
            float4 vrb = *(const float4*)r11;
            {
                float vt = vlt.x + (vrt.x - vlt.x) * fj;
                float vb = vlb.x + (vrb.x - vlb.x) * fj;
                s_tile[c4 + 0][px] = vt + (vb - vt) * fi;
            }
            {
                float vt = vlt.y + (vrt.y - vlt.y) * fj;
                float vb = vlb.y + (vrb.y - vlb.y) * fj;
                s_tile[c4 + 1][px] = vt + (vb - vt) * fi;
            }
            {
                float vt = vlt.z + (vrt.z - vlt.z) * fj;
                float vb = vlb.z + (vrb.z - vlb.z) * fj;
                s_tile[c4 + 2][px] = vt + (vb - vt) * fi;
            }
            {
                float vt = vlt.w + (vrt.w - vlt.w) * fj;
                float vb = vlb.w + (vrb.w - vlb.w) * fj;
                s_tile[c4 + 3][px] = vt + (vb - vt) * fi;
            }
        }
        __syncthreads();
        for (int c = 0; c < Cc; ++c) {
            float a[8], b[8];
            *(float4*)&a[0] = *(const float4*)&s_tile[c][p0];
            *(float4*)&a[4] = *(const float4*)&s_tile[c][p0 + 4];
            *(float4*)&b[0] = *(const float4*)&w_tile[c][f0];
            *(float4*)&b[4] = *(const float4*)&w_tile[c][f0 + 4];
#pragma unroll
            for (int pp = 0; pp < 8; ++pp)
#pragma unroll
                for (int ff = 0; ff < 8; ++ff)
                    acc[pp][ff] = fmaf(a[pp], b[ff], acc[pp][ff]);
        }
        __syncthreads();
    }

    float* orow = out + (size_t)(m * Hh + h) * Wdim * Ff;
#pragma unroll
    for (int pp = 0; pp < 8; ++pp) {
        float4 v0 = make_float4(acc[pp][0], acc[pp][1], acc[pp][2], acc[pp][3]);
        float4 v1 = make_float4(acc[pp][4], acc[pp][5], acc[pp][6], acc[pp][7]);
        *(float4*)&orow[(size_t)(p0 + pp) * Ff + f0]     = v0;
        *(float4*)&orow[(size_t)(p0 + pp) * Ff + f0 + 4] = v1;
    }
}

// ---------------- launch ----------------

extern "C" void kernel_launch(void* const* d_in, const int* in_sizes, int n_in,
                              void* d_out, int out_size, void* d_ws, size_t ws_size,
                              hipStream_t stream) {
    const float* x    = (const float*)d_in[0];
    const float* offs = (const float*)d_in[1];
    const float* W    = (const float*)d_in[2];
    float* out        = (float*)d_out;

    const size_t XH_BYTES = (size_t)8 * 128 * 128 * 64 * 2;   // 16,777,216
    const size_t WT_BYTES = (size_t)9 * 2 * 8 * 64 * 8 * 2;   // 147,456

    if (ws_size >= XH_BYTES + WT_BYTES) {
        __half* xh = (__half*)d_ws;
        __half* wt = (__half*)((char*)d_ws + XH_BYTES);
        cvt_w_kernel<<<dim3(288),  dim3(256), 0, stream>>>(W, wt);
        cvt_x_kernel<<<dim3(4096), dim3(256), 0, stream>>>(x, xh);
        defconv_mfma<<<dim3(2048), dim3(256), 0, stream>>>(offs, xh, wt, out);
    } else {
        defconv_f32<<<dim3(1024), dim3(256), 0, stream>>>(x, offs, W, out);
    }
}

// Round 16
// 57.781 us; speedup vs baseline: 1.6413x; 1.6413x over previous
//
#include <hip/hip_runtime.h>
#include <hip/hip_fp16.h>
#include <cstddef>

// Deformable conv: x(8,128,128,64) f32, offsets(8,128,128,18) f32, W(64,9,128) f32
// out(8,128,128,128) f32.
//
// Round 16: R11 (best: 44us main) + ONE change: the per-tap __syncthreads
// (which emits s_waitcnt vmcnt(0) and force-drains the tap n+2 gathers we
// issued early) is replaced by lgkmcnt(0)+s_barrier. LDS writes stay ordered;
// the 8 in-flight gathers ride across the barrier (consumed next iter under
// compiler-tracked vmcnt). R12-R15 M-split arc abandoned: its (r,g)->(px,octet)
// gather touches 16 scattered 64B lines/instr vs R11's 8 aligned 128B lines
// -> 2x TA work, measured 2x slowdown.
//   prepass A: x -> f16 xh; prepass B: W -> fragment-ordered f16 wt2.
//   main: 2048 blocks (64 px), image-per-XCD swizzle, 4 waves (N-split 32f),
//   LDS param tables, XOR-swizzled double-buffered sampled tile. Per iter n:
//     blend(tap n+1, regs held one full iter) | issue(tap n+2) | MFMA(tap n)

typedef __attribute__((ext_vector_type(8))) _Float16 f16x8;
typedef __attribute__((ext_vector_type(4))) float    f32x4;

struct __align__(16) H2x4 { __half2 a, b, c, d; };

// ---------------- prepass kernels ----------------

__global__ void cvt_x_kernel(const float* __restrict__ x, __half* __restrict__ xh) {
    int i = blockIdx.x * 256 + threadIdx.x;        // 1,048,576 threads * 8 elems
    const float4* p = (const float4*)x + (size_t)i * 2;
    float4 a = p[0], b = p[1];
    H2x4 o;
    o.a = __floats2half2_rn(a.x, a.y);
    o.b = __floats2half2_rn(a.z, a.w);
    o.c = __floats2half2_rn(b.x, b.y);
    o.d = __floats2half2_rn(b.z, b.w);
    ((H2x4*)xh)[i] = o;
}

// Fragment-ordered W: wt2[(((n*4 + wv)*4 + (nf*2+kf))*64 + ln)*8 + e]
//   = W[c][n][f],  c = kf*32 + (ln>>4)*8 + e,  f = wv*32 + nf*16 + (ln&15).
__global__ void cvt_w_kernel(const float* __restrict__ W, __half* __restrict__ wt2) {
    int idx = blockIdx.x * 256 + threadIdx.x;      // 73728 = 9*4*4*64*8
    if (idx >= 9 * 4 * 4 * 64 * 8) return;
    int e  = idx & 7;
    int ln = (idx >> 3) & 63;
    int fr = (idx >> 9) & 3;
    int wv = (idx >> 11) & 3;
    int n  = idx >> 13;
    int nf = fr >> 1, kf = fr & 1;
    int r = ln & 15, g = ln >> 4;
    int c = kf * 32 + g * 8 + e;
    int f = wv * 32 + nf * 16 + r;
    wt2[idx] = __float2half_rn(W[((size_t)c * 9 + n) * 128 + f]);
}

// ---------------- main MFMA kernel ----------------

// sampled tile: [64 px][64 ch] f16, 128 B/row, XOR-swizzled 16B slots:
//   byte(px, slot) = px*128 + ((slot*16) ^ ((px&7)<<4))
// (write: task(px,c8) -> slot c8; read: ch-octet s at slot s^(px&7)).
// Verified: 0 bank conflicts, correct output (R8/R9/R11).

struct Gather {
    H2x4 v00, v01, v10, v11;
    __half2 wA, wB;      // {w00,w01}, {w10,w11}
};

__device__ inline void issue_gather(const char* __restrict__ ximg,
                                    const unsigned short* __restrict__ pb,
                                    const __half2 (*__restrict__ pw)[2],
                                    int px, int c8, Gather& G)
{
    int base = pb[px];
    G.wA = pw[px][0];
    G.wB = pw[px][1];
    int i0 = base >> 7, j0 = base & 127;
    size_t b00 = ((size_t)base << 7) + (c8 << 4);   // bytes; 128 B per pixel
    int di = (i0 < 127) ? (128 * 128) : 0;
    int dj = (j0 < 127) ? 128 : 0;
    G.v00 = *(const H2x4*)(ximg + b00);
    G.v01 = *(const H2x4*)(ximg + b00 + dj);
    G.v10 = *(const H2x4*)(ximg + b00 + di);
    G.v11 = *(const H2x4*)(ximg + b00 + di + dj);
}

__device__ inline void blend_store(char* __restrict__ buf, unsigned byteoff, const Gather& G)
{
    __half2 w00 = __low2half2(G.wA), w01 = __high2half2(G.wA);
    __half2 w10 = __low2half2(G.wB), w11 = __high2half2(G.wB);
    H2x4 r;
    r.a = __hfma2(G.v11.a, w11, __hfma2(G.v10.a, w10, __hfma2(G.v01.a, w01, __hmul2(G.v00.a, w00))));
    r.b = __hfma2(G.v11.b, w11, __hfma2(G.v10.b, w10, __hfma2(G.v01.b, w01, __hmul2(G.v00.b, w00))));
    r.c = __hfma2(G.v11.c, w11, __hfma2(G.v10.c, w10, __hfma2(G.v01.c, w01, __hmul2(G.v00.c, w00))));
    r.d = __hfma2(G.v11.d, w11, __hfma2(G.v10.d, w10, __hfma2(G.v01.d, w01, __hmul2(G.v00.d, w00))));
    *(H2x4*)(buf + byteoff) = r;
}

// barrier that does NOT drain vmcnt: LDS-write visibility only.
__device__ inline void lds_barrier() {
    __builtin_amdgcn_sched_barrier(0);
    asm volatile("s_waitcnt lgkmcnt(0)" ::: "memory");
    __builtin_amdgcn_s_barrier();
    __builtin_amdgcn_sched_barrier(0);
}

__global__ __launch_bounds__(256, 4)
void defconv_mfma(const float* __restrict__ offs,
                  const __half* __restrict__ xh,
                  const __half* __restrict__ wt,
                  float* __restrict__ out)
{
    __shared__ char sbuf[2][64 * 128];             // 16 KB, double-buffered
    __shared__ unsigned short p_base[9][64];       // (i0<<7)|j0
    __shared__ __half2 p_w[9][64][2];              // bilinear corner weights

    const int t = threadIdx.x;

    // XCD swizzle: dispatch i -> XCD i%8 (heuristic); give XCD k image k.
    int bid = blockIdx.x;
    int wid = (bid & 7) * 256 + (bid >> 3);        // bijective, 2048 % 8 == 0
    const int m   = wid >> 8;                      // image == XCD
    const int h   = (wid >> 1) & 127;              // row
    const int q   = wid & 1;                       // px half
    const int pxg = q * 64;

    // ---- phase 0: bilinear params per (px, tap) -> LDS (read offsets ONCE) ----
    const float* offrow = offs + ((size_t)((m * 128 + h) * 128 + pxg)) * 18;
    for (int i = t; i < 576; i += 256) {
        int px = i & 63, n = i >> 6;
        float o0 = offrow[px * 18 + 2 * n];
        float o1 = offrow[px * 18 + 2 * n + 1];
        float ci = fminf(fmaxf((float)h + o0, 0.f), 127.f);
        float cj = fminf(fmaxf((float)(pxg + px) + o1, 0.f), 127.f);
        int i0 = (int)ci;   // floor, ci >= 0
        int j0 = (int)cj;
        float fi = ci - (float)i0, fj = cj - (float)j0;
        float gi = 1.f - fi,       gj = 1.f - fj;
        p_base[n][px] = (unsigned short)((i0 << 7) | j0);
        p_w[n][px][0] = __floats2half2_rn(gi * gj, gi * fj);
        p_w[n][px][1] = __floats2half2_rn(fi * gj, fi * fj);
    }

    const char* ximg = (const char*)(xh + (size_t)m * (128 * 128 * 64));
    const int ln = t & 63;
    const int wv = t >> 6;
    const int r  = ln & 15;
    const int g  = ln >> 4;
    const int n0 = wv * 32;                        // wave's filter strip
    const unsigned rmask = (unsigned)((r & 7) << 4);

    // task split: T0 -> px0 = t>>3 (0..31), T1 -> px0+32 (32..63); c8 = t&7
    const int px0 = t >> 3;
    const int c8  = t & 7;
    const unsigned off0 = (unsigned)(px0 * 128 + ((c8 * 16) ^ ((px0 & 7) << 4)));
    const unsigned off1 = off0 + 32 * 128;

    f32x4 acc[4][2] = {};

    __syncthreads();   // params ready (full drain, once)

    Gather G0, G1;

    // ---- prologue: stage tap 0 fully; prefetch tap 1 into regs ----
    issue_gather(ximg, p_base[0], p_w[0], px0,      c8, G0);
    issue_gather(ximg, p_base[0], p_w[0], px0 + 32, c8, G1);
    blend_store(sbuf[0], off0, G0);
    blend_store(sbuf[0], off1, G1);
    issue_gather(ximg, p_base[1], p_w[1], px0,      c8, G0);
    issue_gather(ximg, p_base[1], p_w[1], px0 + 32, c8, G1);
    lds_barrier();

#pragma unroll 2
    for (int n = 0; n < 9; ++n) {
        char* cur = sbuf[n & 1];
        char* nxt = sbuf[(n + 1) & 1];

        // B fragments for tap n — fragment-ordered, fully coalesced 1KB/instr
        f16x8 bfrag[2][2];
        const __half* wb = wt + (size_t)(n * 4 + wv) * (4 * 512);
#pragma unroll
        for (int nf = 0; nf < 2; ++nf)
#pragma unroll
            for (int kf = 0; kf < 2; ++kf)
                bfrag[nf][kf] = *(const f16x8*)(wb + ((nf * 2 + kf) * 64 + ln) * 8);

        // blend tap n+1 (loads issued a FULL iteration ago), refill with tap n+2
        if (n < 8) blend_store(nxt, off0, G0);
        if (n < 7) issue_gather(ximg, p_base[n + 2], p_w[n + 2], px0, c8, G0);

        __builtin_amdgcn_s_setprio(1);
#pragma unroll
        for (int mf = 0; mf < 2; ++mf) {
            int row = mf * 16 + r;
            unsigned o0 = (unsigned)(row * 128) + ((unsigned)(g * 16)      ^ rmask);
            unsigned o1 = (unsigned)(row * 128) + ((unsigned)(g * 16 + 64) ^ rmask);
            f16x8 a0 = *(const f16x8*)(cur + o0);
            f16x8 a1 = *(const f16x8*)(cur + o1);
            acc[mf][0] = __builtin_amdgcn_mfma_f32_16x16x32_f16(a0, bfrag[0][0], acc[mf][0], 0, 0, 0);
            acc[mf][1] = __builtin_amdgcn_mfma_f32_16x16x32_f16(a0, bfrag[1][0], acc[mf][1], 0, 0, 0);
            acc[mf][0] = __builtin_amdgcn_mfma_f32_16x16x32_f16(a1, bfrag[0][1], acc[mf][0], 0, 0, 0);
            acc[mf][1] = __builtin_amdgcn_mfma_f32_16x16x32_f16(a1, bfrag[1][1], acc[mf][1], 0, 0, 0);
        }
        __builtin_amdgcn_s_setprio(0);

        if (n < 8) blend_store(nxt, off1, G1);
        if (n < 7) issue_gather(ximg, p_base[n + 2], p_w[n + 2], px0 + 32, c8, G1);

        __builtin_amdgcn_s_setprio(1);
#pragma unroll
        for (int mf = 2; mf < 4; ++mf) {
            int row = mf * 16 + r;
            unsigned o0 = (unsigned)(row * 128) + ((unsigned)(g * 16)      ^ rmask);
            unsigned o1 = (unsigned)(row * 128) + ((unsigned)(g * 16 + 64) ^ rmask);
            f16x8 a0 = *(const f16x8*)(cur + o0);
            f16x8 a1 = *(const f16x8*)(cur + o1);
            acc[mf][0] = __builtin_amdgcn_mfma_f32_16x16x32_f16(a0, bfrag[0][0], acc[mf][0], 0, 0, 0);
            acc[mf][1] = __builtin_amdgcn_mfma_f32_16x16x32_f16(a0, bfrag[1][0], acc[mf][1], 0, 0, 0);
            acc[mf][0] = __builtin_amdgcn_mfma_f32_16x16x32_f16(a1, bfrag[0][1], acc[mf][0], 0, 0, 0);
            acc[mf][1] = __builtin_amdgcn_mfma_f32_16x16x32_f16(a1, bfrag[1][1], acc[mf][1], 0, 0, 0);
        }
        __builtin_amdgcn_s_setprio(0);

        // LDS-visibility barrier ONLY: in-flight gathers ride across.
        lds_barrier();
    }

    // ---- epilogue: D[px][f], col = lane&15 -> f, row = (lane>>4)*4 + reg -> px ----
    float* orow = out + ((size_t)((m * 128 + h) * 128 + pxg)) * 128;
#pragma unroll
    for (int mf = 0; mf < 4; ++mf)
#pragma unroll
        for (int nf = 0; nf < 2; ++nf) {
            int f    = n0 + nf * 16 + r;
            int px0e = mf * 16 + g * 4;
#pragma unroll
            for (int qq = 0; qq < 4; ++qq)
                orow[(size_t)(px0e + qq) * 128 + f] = acc[mf][nf][qq];
        }
}

// ---------------- fp32 fallback (if ws too small) ----------------

constexpr int Hh   = 128;
constexpr int Wdim = 128;
constexpr int Cc   = 64;
constexpr int NTAP = 9;
constexpr int Ff   = 128;
constexpr int PXB  = 128;
constexpr int SPAD = 132;

__global__ __launch_bounds__(256, 2)
void defconv_f32(const float* __restrict__ x,
                 const float* __restrict__ offs,
                 const float* __restrict__ Wt,
                 float* __restrict__ out)
{
    __shared__ float s_tile[Cc][SPAD];
    __shared__ float w_tile[Cc][Ff];
    __shared__ float off_lds[PXB * 2 * NTAP];

    const int t   = threadIdx.x;
    const int bid = blockIdx.x;
    const int m   = bid >> 7;
    const int h   = bid & 127;

    const float* offrow = offs + (size_t)(m * Hh + h) * Wdim * (2 * NTAP);
    for (int i = t; i < PXB * 2 * NTAP; i += 256) off_lds[i] = offrow[i];

    const int pg = t & 15;
    const int fg = t >> 4;
    const int p0 = pg * 8;
    const int f0 = fg * 8;

    float acc[8][8];
#pragma unroll
    for (int a = 0; a < 8; ++a)
#pragma unroll
        for (int b = 0; b < 8; ++b) acc[a][b] = 0.f;

    const float* xbase = x + (size_t)m * Hh * Wdim * Cc;
    __syncthreads();

    for (int n = 0; n < NTAP; ++n) {
#pragma unroll
        for (int i = 0; i < 8; ++i) {
            int idx = t + 256 * i;
            int c   = idx >> 5;
            int f4  = (idx & 31) * 4;
            *(float4*)&w_tile[c][f4] =
                *(const float4*)(Wt + ((size_t)c * NTAP + n) * Ff + f4);
        }
#pragma unroll
        for (int i = 0; i < 8; ++i) {
            int task = t + 256 * i;
            int px   = task >> 4;
            int c4   = (task & 15) * 4;
            float o0 = off_lds[px * (2 * NTAP) + 2 * n];
            float o1 = off_lds[px * (2 * NTAP) + 2 * n + 1];
            float ci = fminf(fmaxf((float)h  + o0, 0.f), 127.f);
            float cj = fminf(fmaxf((float)px + o1, 0.f), 127.f);
            int i0 = (int)floorf(ci);
            int i1 = (int)ceilf(ci);
            int j0 = (int)floorf(cj);
            int j1 = (int)ceilf(cj);
            float fi = ci - (float)i0;
            float fj = cj - (float)j0;
            const float* r00 = xbase + ((size_t)i0 * Wdim + j0) * Cc + c4;
            const float* r01 = xbase + ((size_t)i0 * Wdim + j1) * Cc + c4;
            const float* r10 = xbase + ((size_t)i1 * Wdim + j0) * Cc + c4;
            const float* r11 = xbase + ((size_t)i1 * Wdim + j1) * Cc + c4;
            float4 vlt = *(const float4*)r00;
            float4 vrt = *(const float4*)r01;
            float4 vlb = *(const float4*)r10;
            float4 vrb = *(const float4*)r11;
            {
                float vt = vlt.x + (vrt.x - vlt.x) * fj;
                float vb = vlb.x + (vrb.x - vlb.x) * fj;
                s_tile[c4 + 0][px] = vt + (vb - vt) * fi;
            }
            {
                float vt = vlt.y + (vrt.y - vlt.y) * fj;
                float vb = vlb.y + (vrb.y - vlb.y) * fj;
                s_tile[c4 + 1][px] = vt + (vb - vt) * fi;
            }
            {
                float vt = vlt.z + (vrt.z - vlt.z) * fj;
                float vb = vlb.z + (vrb.z - vlb.z) * fj;
                s_tile[c4 + 2][px] = vt + (vb - vt) * fi;
            }
            {
                float vt = vlt.w + (vrt.w - vlt.w) * fj;
                float vb = vlb.w + (vrb.w - vlb.w) * fj;
                s_tile[c4 + 3][px] = vt + (vb - vt) * fi;
            }
        }
        __syncthreads();
        for (int c = 0; c < Cc; ++c) {
            float a[8], b[8];
            *(float4*)&a[0] = *(const float4*)&s_tile[c][p0];
            *(float4*)&a[4] = *(const float4*)&s_tile[c][p0 + 4];
            *(float4*)&b[0] = *(const float4*)&w_tile[c][f0];
            *(float4*)&b[4] = *(const float4*)&w_tile[c][f0 + 4];
#pragma unroll
            for (int pp = 0; pp < 8; ++pp)
#pragma unroll
                for (int ff = 0; ff < 8; ++ff)
                    acc[pp][ff] = fmaf(a[pp], b[ff], acc[pp][ff]);
        }
        __syncthreads();
    }

    float* orow = out + (size_t)(m * Hh + h) * Wdim * Ff;
#pragma unroll
    for (int pp = 0; pp < 8; ++pp) {
        float4 v0 = make_float4(acc[pp][0], acc[pp][1], acc[pp][2], acc[pp][3]);
        float4 v1 = make_float4(acc[pp][4], acc[pp][5], acc[pp][6], acc[pp][7]);
        *(float4*)&orow[(size_t)(p0 + pp) * Ff + f0]     = v0;
        *(float4*)&orow[(size_t)(p0 + pp) * Ff + f0 + 4] = v1;
    }
}

// ---------------- launch ----------------

extern "C" void kernel_launch(void* const* d_in, const int* in_sizes, int n_in,
                              void* d_out, int out_size, void* d_ws, size_t ws_size,
                              hipStream_t stream) {
    const float* x    = (const float*)d_in[0];
    const float* offs = (const float*)d_in[1];
    const float* W    = (const float*)d_in[2];
    float* out        = (float*)d_out;

    const size_t XH_BYTES = (size_t)8 * 128 * 128 * 64 * 2;   // 16,777,216
    const size_t WT_BYTES = (size_t)9 * 4 * 4 * 64 * 8 * 2;   // 147,456

    if (ws_size >= XH_BYTES + WT_BYTES) {
        __half* xh = (__half*)d_ws;
        __half* wt = (__half*)((char*)d_ws + XH_BYTES);
        cvt_w_kernel<<<dim3(288),  dim3(256), 0, stream>>>(W, wt);
        cvt_x_kernel<<<dim3(4096), dim3(256), 0, stream>>>(x, xh);
        defconv_mfma<<<dim3(2048), dim3(256), 0, stream>>>(offs, xh, wt, out);
    } else {
        defconv_f32<<<dim3(1024), dim3(256), 0, stream>>>(x, offs, W, out);
    }
}